// Round 8
// baseline (105.884 us; speedup 1.0000x reference)
//
#include <hip/hip_runtime.h>
#include <hip/hip_fp16.h>

constexpr int B  = 8;
constexpr int N  = 1024;
constexpr int FI = 64;
constexpr int FO = 128;
constexpr int NH = 4;
constexpr float LOG2E = 1.4426950408889634f;

using half8 = __attribute__((ext_vector_type(8))) _Float16;
using f32x4 = __attribute__((ext_vector_type(4))) float;

union I8 { int4 v[2]; int s[8]; };
union F8 { float4 v[2]; float s[8]; };

__device__ __forceinline__ unsigned h2pack(float a, float b) {
  __half2 r = __float22half2_rn(make_float2(a, b));
  union { __half2 h; unsigned u; } c; c.h = r; return c.u;
}
__device__ __forceinline__ float h2f(unsigned short u) {
  union { unsigned short s; _Float16 h; } c; c.s = u; return (float)c.h;
}
__device__ __forceinline__ unsigned short f2h(float f) {
  __half hv = __float2half(f);
  return *reinterpret_cast<unsigned short*>(&hv);
}

// ---------------------------------------------------------------------------
// Kernel 1 (merged): blocks 0..511 = proj (h=x@W -> es/edt + h16 fp16),
// blocks 512..1023 = mask (mew = adj ? fp16(ew) : -0.0). R3-proven form.
// h16 layout: [b][ft(8)][s(32)][lane(64)][8], lane=n+16*kq, j=s*32+kq*8+u.
// ---------------------------------------------------------------------------
__global__ __launch_bounds__(256, 2) void gat_prep(
    const float* __restrict__ x, const float* __restrict__ W,
    const float* __restrict__ a, const int* __restrict__ adj,
    const float* __restrict__ ew,
    unsigned short* __restrict__ h16,
    float* __restrict__ es, float* __restrict__ edt,
    unsigned short* __restrict__ mew) {
  const int t = threadIdx.x;
  if (blockIdx.x >= 512) {        // ---- mask part ----
    const size_t base = ((size_t)(blockIdx.x - 512) * 256 + t) * 8;
    I8 aj; aj.v[0] = *(const int4*)(adj + base); aj.v[1] = *(const int4*)(adj + base + 4);
    F8 e;  e.v[0]  = *(const float4*)(ew + base); e.v[1]  = *(const float4*)(ew + base + 4);
    union { unsigned short u[8]; uint4 v; } o;
    #pragma unroll
    for (int u = 0; u < 8; ++u)
      o.u[u] = aj.s[u] ? f2h(e.s[u]) : (unsigned short)0x8000;   // -0.0 when masked
    *(uint4*)(mew + base) = o.v;
    return;
  }
  // ---- proj part ----
  __shared__ float xs[16 * FI];
  const int row0 = blockIdx.x * 16;
  for (int i = t; i < 16 * FI; i += 256) xs[i] = x[row0 * FI + i];
  const int f  = t & 127;
  const int rh = t >> 7;
  float wc[FI];
  #pragma unroll
  for (int k = 0; k < FI; ++k) wc[k] = W[k * FO + f];
  const int hh = f >> 5, d = f & 31;
  const float a_s = a[hh * 64 + d] * LOG2E;
  const float a_d = a[hh * 64 + 32 + d] * LOG2E;
  __syncthreads();
  float acc8[8];
  #pragma unroll
  for (int r = 0; r < 8; ++r) {
    const int lr = rh * 8 + r;
    const float4* xr = (const float4*)(xs + lr * FI);
    float acc = 0.f;
    #pragma unroll
    for (int kq = 0; kq < FI / 4; ++kq) {
      const float4 xv = xr[kq];
      acc += xv.x * wc[4*kq] + xv.y * wc[4*kq+1] + xv.z * wc[4*kq+2] + xv.w * wc[4*kq+3];
    }
    acc8[r] = acc;
    float ps = acc * a_s, pd = acc * a_d;
    #pragma unroll
    for (int off = 16; off; off >>= 1) {
      ps += __shfl_xor(ps, off, 64);
      pd += __shfl_xor(pd, off, 64);
    }
    const int row = row0 + lr;
    if (d == 0) {
      es[row * NH + hh] = ps;
      edt[((size_t)((row >> 10) * NH + hh)) * N + (row & 1023)] = pd;
    }
  }
  const int bb = row0 >> 10;
  const int jl = (row0 & 1023) + rh * 8;
  union { unsigned short u16[8]; uint4 v; } hv;
  #pragma unroll
  for (int r = 0; r < 8; ++r) hv.u16[r] = f2h(acc8[r]);
  const int ft = f >> 4, n = f & 15;
  const int sS = jl >> 5, kq2 = (jl >> 3) & 3;
  const size_t base = (size_t)bb * (FO * N)
                    + ((size_t)(ft * 32 + sS) * 64 + (n + 16 * kq2)) * 8;
  *(uint4*)(h16 + base) = hv.v;
}

// ---------------------------------------------------------------------------
// Kernel 1.5 (R18): denominator prepass. dinv[b,i,h] = 1/sum_j sgn*exp2(
// leaky(es+ed)). One WAVE per (b,i) row: 2048 blocks x 256 thr, no LDS, no
// barriers, pure streaming+VALU at 16 waves/CU -> runs at issue rate. This
// breaks attn's denominator->avg ordering constraint so attn needs only ONE
// N^2 pass (P1 writes avg inline; tail pass deleted).
// ---------------------------------------------------------------------------
__global__ __launch_bounds__(256, 4) void gat_denom(
    const float* __restrict__ es, const float* __restrict__ edt,
    const unsigned short* __restrict__ mew,
    float* __restrict__ dinv) {
  const int blk = blockIdx.x;             // b*(N/4) + ig
  const int b   = blk >> 8;               // N/4 = 256 blocks per b
  const int gi  = ((blk & 255) << 2) + (threadIdx.x >> 6);
  const int lane = threadIdx.x & 63;
  float esv[4];
  { const float4 e4 = *(const float4*)(es + ((size_t)b * N + gi) * NH);
    esv[0] = e4.x; esv[1] = e4.y; esv[2] = e4.z; esv[3] = e4.w; }
  const int j0 = lane * 16;
  union { uint2 v; unsigned short u[4]; } mw[4];
  #pragma unroll
  for (int q = 0; q < 4; ++q)
    mw[q].v = *(const uint2*)(mew + (size_t)gi * N + j0 + q * 4);
  float d[4] = {0.f, 0.f, 0.f, 0.f};
  #pragma unroll
  for (int h = 0; h < 4; ++h) {
    const float* ep = edt + ((size_t)(b * NH + h)) * N + j0;
    #pragma unroll
    for (int q = 0; q < 4; ++q) {
      const float4 ev = *(const float4*)(ep + q * 4);
      #pragma unroll
      for (int u = 0; u < 4; ++u) {
        float e = esv[h] + (&ev.x)[u];
        e = fmaxf(e, 0.2f * e);
        const float sgn = (mw[q].u[u] >> 15) ? 0.f : 1.f;
        d[h] = fmaf(__builtin_amdgcn_exp2f(e), sgn, d[h]);
      }
    }
  }
  #pragma unroll
  for (int h = 0; h < 4; ++h) {
    float v = d[h];
    v += __shfl_xor(v, 1, 64);  v += __shfl_xor(v, 2, 64);
    v += __shfl_xor(v, 4, 64);  v += __shfl_xor(v, 8, 64);
    v += __shfl_xor(v, 16, 64); v += __shfl_xor(v, 32, 64);
    d[h] = v;
  }
  if (lane == 0) {
    float4 o;
    o.x = d[0] > 0.f ? 1.0f / d[0] : 0.f;
    o.y = d[1] > 0.f ? 1.0f / d[1] : 0.f;
    o.z = d[2] > 0.f ? 1.0f / d[2] : 0.f;
    o.w = d[3] > 0.f ? 1.0f / d[3] : 0.f;
    *(float4*)(dinv + ((size_t)b * N + gi) * NH) = o;
  }
}

// ---------------------------------------------------------------------------
// Kernel 2: attention out + avg, SINGLE N^2 pass (R18). 512 thr, 16-row
// tiles, 512 blocks, proven (512,4) config. With dinv precomputed, P1 writes
// avg inline (0.25*mfa*sum_h p*inv4[h]) and the old recompute tail, dpart
// accumulators, sgn handling, and shuffle-reduce epilogue are all deleted.
// pk->fp16->MFMA path and pew addressing unchanged (R3-proven u-pair form).
// LDS: pew 32K + edt 16K = 48.3 KB; 2 blocks/CU.
// ---------------------------------------------------------------------------
__global__ __launch_bounds__(512, 4) void gat_attn(
    const unsigned short* __restrict__ h16,
    const float* __restrict__ es, const float* __restrict__ edt,
    const unsigned short* __restrict__ mew,
    const float* __restrict__ dinv,
    float* __restrict__ out, float* __restrict__ avg) {
  __shared__ unsigned short pew[2][4 * 2048];
  __shared__ float edt_lds[NH * N];       // [h][j] fp32, 16 KB
  const int t  = threadIdx.x;
  const int b  = blockIdx.x & 7;
  const int i0 = (blockIdx.x >> 3) << 4;
  // P1 ids
  const int il = t >> 5, jq = t & 31;
  const int gi = i0 + il;
  float esv[4], inv4[4];
  { const float4 e4 = *(const float4*)(es + ((size_t)b * N + gi) * NH);
    esv[0] = e4.x; esv[1] = e4.y; esv[2] = e4.z; esv[3] = e4.w; }
  { const float4 v4 = *(const float4*)(dinv + ((size_t)b * N + gi) * NH);
    inv4[0] = v4.x; inv4[1] = v4.y; inv4[2] = v4.z; inv4[3] = v4.w; }
  // P2 ids
  const int lane = t & 63, wave = t >> 6;
  const int hh = wave & 3, nt2 = wave >> 2;
  const int m = lane & 15, kq = lane >> 4;
  const int ft = hh * 2 + nt2;
  const unsigned short* hbp = h16 + (size_t)b * (FO * N) + (size_t)(ft * 32) * 512 + lane * 8;
  f32x4 acc0 = {0.f,0.f,0.f,0.f}, acc1 = {0.f,0.f,0.f,0.f};

  uint2  rmw;            // P1 prefetch reg (mew only)
  half8  Bf[4];          // B regs (single set, fp16)

  auto ld_p1 = [&](int c) {
    const int jb = c * 128 + jq * 4;
    rmw = *(const uint2*)(mew + (size_t)gi * N + jb);
  };
  auto ld_B = [&](int c) {
    const size_t so = (size_t)c * 4 * 512;
    #pragma unroll
    for (int ks = 0; ks < 4; ++ks)
      Bf[ks] = *reinterpret_cast<const half8*>(hbp + so + (size_t)ks * 512);
  };
  auto p1_compute = [&](int c) {
    const int buf = c & 1;
    const int jb = c * 128 + jq * 4;
    union { uint2 v; unsigned short u[4]; } mw; mw.v = rmw;
    float4 red[4];
    #pragma unroll
    for (int h = 0; h < 4; ++h)
      red[h] = *(const float4*)(&edt_lds[h * N + jb]);   // LDS broadcast
    const int g = jq >> 1, half = jq & 1;
    const int o = ((g * 16 + il) ^ (g & 7)) * 8 + half * 4;
    float4 r;                                            // avg out (inline)
    float* rp = &r.x;
    #pragma unroll
    for (int up = 0; up < 2; ++up) {        // u-pairs: minimizes live temps
      float pk[4][2];
      #pragma unroll
      for (int uu = 0; uu < 2; ++uu) {
        const int u = up * 2 + uu;
        const float mfa = h2f((unsigned short)(mw.u[u] & 0x7fff));
        float sv = 0.f;
        #pragma unroll
        for (int h = 0; h < 4; ++h) {
          float e = esv[h] + (&red[h].x)[u];
          e = fmaxf(e, 0.2f * e);
          const float p = __builtin_amdgcn_exp2f(e);
          pk[h][uu] = p * mfa;
          sv = fmaf(p, inv4[h], sv);
        }
        rp[u] = 0.25f * mfa * sv;           // masked: mfa=0 -> 0
      }
      #pragma unroll
      for (int h = 0; h < 4; ++h)
        *(unsigned*)(pew[buf] + h * 2048 + o + up * 2) = h2pack(pk[h][0], pk[h][1]);
    }
    *(float4*)(avg + ((size_t)b * N + gi) * N + jb) = r;
  };
  auto p2_step = [&](int c) {
    const int buf = c & 1;
    #pragma unroll
    for (int ks = 0; ks < 4; ++ks) {
      const int g2 = ks * 4 + kq;
      const int o2 = ((g2 * 16 + m) ^ (g2 & 7)) * 8;
      half8 afr;
      { uint4 tmp = *(const uint4*)(pew[buf] + hh * 2048 + o2);
        __builtin_memcpy(&afr, &tmp, 16); }
      if (ks & 1)
        acc1 = __builtin_amdgcn_mfma_f32_16x16x32_f16(afr, Bf[ks], acc1, 0, 0, 0);
      else
        acc0 = __builtin_amdgcn_mfma_f32_16x16x32_f16(afr, Bf[ks], acc0, 0, 0, 0);
    }
  };

  // ---- prologue: stage edt -> LDS (one-time), first loads ----
  { const float4* src = (const float4*)(edt + (size_t)b * NH * N);
    float4* dst = (float4*)edt_lds;
    dst[t]       = src[t];          // 512 x 16B = 8 KB
    dst[t + 512] = src[t + 512]; }  // 8 KB
  ld_B(0);
  ld_p1(0);
  __syncthreads();                  // edt_lds visible
  p1_compute(0);
  ld_p1(1);
  __syncthreads();                  // pew[0] visible

  // ---- main loop: NOT unrolled (keeps single-buffer regs single) ----
  #pragma unroll 1
  for (int c = 0; c < 8; ++c) {
    p2_step(c);                       // consumes B(c) + pew[c&1]
    if (c + 1 < 8) {
      ld_B(c + 1);                    // refill B; ~1 chunk in flight before use
      p1_compute(c + 1);              // consumes rmw(c+1), writes pew[(c+1)&1]
      if (c + 2 < 8) ld_p1(c + 2);    // refill rmw
      __syncthreads();
    }
  }

  // ---- out = acc_sum * inv (fp32; inv from dinv, L2-hot) ----
  #pragma unroll
  for (int reg = 0; reg < 4; ++reg) {
    const int row = kq * 4 + reg;              // D: col=lane&15, row=quad*4+reg
    const float inv = dinv[((size_t)b * N + i0 + row) * NH + hh];
    out[((size_t)b * N + i0 + row) * FO + hh * 32 + nt2 * 16 + m]
        = (acc0[reg] + acc1[reg]) * inv;
  }
}

// ---------------------------------------------------------------------------
extern "C" void kernel_launch(void* const* d_in, const int* in_sizes, int n_in,
                              void* d_out, int out_size, void* d_ws, size_t ws_size,
                              hipStream_t stream) {
  const float* x   = (const float*)d_in[0];
  const int*   adj = (const int*)d_in[1];
  const float* ewt = (const float*)d_in[2];
  const float* W   = (const float*)d_in[3];
  const float* a   = (const float*)d_in[4];

  float* out = (float*)d_out;                  // [B,N,128]
  float* avg = out + (size_t)B * N * FO;       // [B,N,N]

  unsigned short* h16 = (unsigned short*)d_ws;        // h fp16 frag, 2 MB
  unsigned short* mew = h16 + (size_t)B * FO * N;     // [N,N] fp16 masked, 2 MB
  float* es   = (float*)(mew + (size_t)N * N);        // [B*N, 4]
  float* edt  = es + (size_t)B * N * NH;              // [B, 4, N]
  float* dinv = edt + (size_t)B * NH * N;             // [B*N, 4]

  gat_prep<<<1024, 256, 0, stream>>>(x, W, a, adj, ewt, h16, es, edt, mew);
  gat_denom<<<B * (N / 4), 256, 0, stream>>>(es, edt, mew, dinv);
  gat_attn<<<B * (N / 16), 512, 0, stream>>>(h16, es, edt, mew, dinv, out, avg);
}

// Round 9
// 100.747 us; speedup vs baseline: 1.0510x; 1.0510x over previous
//
#include <hip/hip_runtime.h>
#include <hip/hip_fp16.h>

constexpr int B  = 8;
constexpr int N  = 1024;
constexpr int FI = 64;
constexpr int FO = 128;
constexpr int NH = 4;
constexpr float LOG2E = 1.4426950408889634f;

using half8 = __attribute__((ext_vector_type(8))) _Float16;
using f32x4 = __attribute__((ext_vector_type(4))) float;

union I8 { int4 v[2]; int s[8]; };
union F8 { float4 v[2]; float s[8]; };

__device__ __forceinline__ unsigned h2pack(float a, float b) {
  __half2 r = __float22half2_rn(make_float2(a, b));
  union { __half2 h; unsigned u; } c; c.h = r; return c.u;
}
__device__ __forceinline__ float h2f(unsigned short u) {
  union { unsigned short s; _Float16 h; } c; c.s = u; return (float)c.h;
}
__device__ __forceinline__ unsigned short f2h(float f) {
  __half hv = __float2half(f);
  return *reinterpret_cast<unsigned short*>(&hv);
}

// ---------------------------------------------------------------------------
// Kernel 1 (merged): blocks 0..511 = proj (h=x@W -> es/edt + h16 fp16),
// blocks 512..1023 = mask (mew = adj ? fp16(ew) : -0.0). R3-proven form
// (session best, 101.7us). Tested-and-rejected alternates: exp-table
// factorization (R2, +7.3), W-LDS staging (R5, +0.8), tighter launch
// bounds (R4, spills).
// h16 layout: [b][ft(8)][s(32)][lane(64)][8], lane=n+16*kq, j=s*32+kq*8+u.
// ---------------------------------------------------------------------------
__global__ __launch_bounds__(256, 2) void gat_prep(
    const float* __restrict__ x, const float* __restrict__ W,
    const float* __restrict__ a, const int* __restrict__ adj,
    const float* __restrict__ ew,
    unsigned short* __restrict__ h16,
    float* __restrict__ es, float* __restrict__ edt,
    unsigned short* __restrict__ mew) {
  const int t = threadIdx.x;
  if (blockIdx.x >= 512) {        // ---- mask part ----
    const size_t base = ((size_t)(blockIdx.x - 512) * 256 + t) * 8;
    I8 aj; aj.v[0] = *(const int4*)(adj + base); aj.v[1] = *(const int4*)(adj + base + 4);
    F8 e;  e.v[0]  = *(const float4*)(ew + base); e.v[1]  = *(const float4*)(ew + base + 4);
    union { unsigned short u[8]; uint4 v; } o;
    #pragma unroll
    for (int u = 0; u < 8; ++u)
      o.u[u] = aj.s[u] ? f2h(e.s[u]) : (unsigned short)0x8000;   // -0.0 when masked
    *(uint4*)(mew + base) = o.v;
    return;
  }
  // ---- proj part ----
  __shared__ float xs[16 * FI];
  const int row0 = blockIdx.x * 16;
  for (int i = t; i < 16 * FI; i += 256) xs[i] = x[row0 * FI + i];
  const int f  = t & 127;
  const int rh = t >> 7;
  float wc[FI];
  #pragma unroll
  for (int k = 0; k < FI; ++k) wc[k] = W[k * FO + f];
  const int hh = f >> 5, d = f & 31;
  const float a_s = a[hh * 64 + d] * LOG2E;
  const float a_d = a[hh * 64 + 32 + d] * LOG2E;
  __syncthreads();
  float acc8[8];
  #pragma unroll
  for (int r = 0; r < 8; ++r) {
    const int lr = rh * 8 + r;
    const float4* xr = (const float4*)(xs + lr * FI);
    float acc = 0.f;
    #pragma unroll
    for (int kq = 0; kq < FI / 4; ++kq) {
      const float4 xv = xr[kq];
      acc += xv.x * wc[4*kq] + xv.y * wc[4*kq+1] + xv.z * wc[4*kq+2] + xv.w * wc[4*kq+3];
    }
    acc8[r] = acc;
    float ps = acc * a_s, pd = acc * a_d;
    #pragma unroll
    for (int off = 16; off; off >>= 1) {
      ps += __shfl_xor(ps, off, 64);
      pd += __shfl_xor(pd, off, 64);
    }
    const int row = row0 + lr;
    if (d == 0) {
      es[row * NH + hh] = ps;
      edt[((size_t)((row >> 10) * NH + hh)) * N + (row & 1023)] = pd;
    }
  }
  const int bb = row0 >> 10;
  const int jl = (row0 & 1023) + rh * 8;
  union { unsigned short u16[8]; uint4 v; } hv;
  #pragma unroll
  for (int r = 0; r < 8; ++r) hv.u16[r] = f2h(acc8[r]);
  const int ft = f >> 4, n = f & 15;
  const int sS = jl >> 5, kq2 = (jl >> 3) & 3;
  const size_t base = (size_t)bb * (FO * N)
                    + ((size_t)(ft * 32 + sS) * 64 + (n + 16 * kq2)) * 8;
  *(uint4*)(h16 + base) = hv.v;
}

// ---------------------------------------------------------------------------
// Kernel 2: attention out + fused avg. 512 thr, 16-row tiles, 512 blocks.
// R3-proven configuration (session best, 101.7us): (512,4) bounds ->
// 2 blocks/CU; single B-buffer pipeline; edt staged once into LDS; fused
// avg recompute tail (overlaps other blocks' main loops).
// Tested-and-rejected alternates: (512,6)+lean-P1 (R6, +2.9), 32-row
// tiles (R7, +1.5), denom-prepass single-pass (R8, +4.2).
// LDS: pew 32K + edt 16K + dvl = 49.4 KB.
// ---------------------------------------------------------------------------
__global__ __launch_bounds__(512, 4) void gat_attn(
    const unsigned short* __restrict__ h16,
    const float* __restrict__ es, const float* __restrict__ edt,
    const unsigned short* __restrict__ mew,
    float* __restrict__ out, float* __restrict__ avg) {
  __shared__ unsigned short pew[2][4 * 2048];
  __shared__ float edt_lds[NH * N];       // [h][j] fp32, 16 KB
  __shared__ float dvl[64];
  const int t  = threadIdx.x;
  const int b  = blockIdx.x & 7;
  const int i0 = (blockIdx.x >> 3) << 4;
  // P1 ids
  const int il = t >> 5, jq = t & 31;
  const int gi = i0 + il;
  float esv[4];
  { const float4 e4 = *(const float4*)(es + ((size_t)b * N + gi) * NH);
    esv[0] = e4.x; esv[1] = e4.y; esv[2] = e4.z; esv[3] = e4.w; }
  // P2 ids
  const int lane = t & 63, wave = t >> 6;
  const int hh = wave & 3, nt2 = wave >> 2;
  const int m = lane & 15, kq = lane >> 4;
  const int ft = hh * 2 + nt2;
  const unsigned short* hbp = h16 + (size_t)b * (FO * N) + (size_t)(ft * 32) * 512 + lane * 8;
  f32x4 acc0 = {0.f,0.f,0.f,0.f}, acc1 = {0.f,0.f,0.f,0.f};
  float dpart[4] = {0.f, 0.f, 0.f, 0.f};

  uint2  rmw;            // P1 prefetch reg (mew only)
  half8  Bf[4];          // B regs (single set, fp16)

  auto ld_p1 = [&](int c) {
    const int jb = c * 128 + jq * 4;
    rmw = *(const uint2*)(mew + (size_t)gi * N + jb);
  };
  auto ld_B = [&](int c) {
    const size_t so = (size_t)c * 4 * 512;
    #pragma unroll
    for (int ks = 0; ks < 4; ++ks)
      Bf[ks] = *reinterpret_cast<const half8*>(hbp + so + (size_t)ks * 512);
  };
  auto p1_compute = [&](int c) {
    const int buf = c & 1;
    const int jb = c * 128 + jq * 4;
    union { uint2 v; unsigned short u[4]; } mw; mw.v = rmw;
    float4 red[4];
    #pragma unroll
    for (int h = 0; h < 4; ++h)
      red[h] = *(const float4*)(&edt_lds[h * N + jb]);   // LDS broadcast
    const int g = jq >> 1, half = jq & 1;
    const int o = ((g * 16 + il) ^ (g & 7)) * 8 + half * 4;
    #pragma unroll
    for (int up = 0; up < 2; ++up) {        // u-pairs: minimizes live temps
      float pk[4][2];
      #pragma unroll
      for (int uu = 0; uu < 2; ++uu) {
        const int u = up * 2 + uu;
        const float mfa = h2f((unsigned short)(mw.u[u] & 0x7fff));
        const float sgn = (mw.u[u] >> 15) ? 0.f : 1.f;
        #pragma unroll
        for (int h = 0; h < 4; ++h) {
          float e = esv[h] + (&red[h].x)[u];
          e = fmaxf(e, 0.2f * e);
          const float p = __builtin_amdgcn_exp2f(e);
          pk[h][uu] = p * mfa;
          dpart[h] = fmaf(p, sgn, dpart[h]);
        }
      }
      #pragma unroll
      for (int h = 0; h < 4; ++h)
        *(unsigned*)(pew[buf] + h * 2048 + o + up * 2) = h2pack(pk[h][0], pk[h][1]);
    }
  };
  auto p2_step = [&](int c) {
    const int buf = c & 1;
    #pragma unroll
    for (int ks = 0; ks < 4; ++ks) {
      const int g2 = ks * 4 + kq;
      const int o2 = ((g2 * 16 + m) ^ (g2 & 7)) * 8;
      half8 afr;
      { uint4 tmp = *(const uint4*)(pew[buf] + hh * 2048 + o2);
        __builtin_memcpy(&afr, &tmp, 16); }
      if (ks & 1)
        acc1 = __builtin_amdgcn_mfma_f32_16x16x32_f16(afr, Bf[ks], acc1, 0, 0, 0);
      else
        acc0 = __builtin_amdgcn_mfma_f32_16x16x32_f16(afr, Bf[ks], acc0, 0, 0, 0);
    }
  };

  // ---- prologue: stage edt -> LDS (one-time), first loads ----
  { const float4* src = (const float4*)(edt + (size_t)b * NH * N);
    float4* dst = (float4*)edt_lds;
    dst[t]       = src[t];          // 512 x 16B = 8 KB
    dst[t + 512] = src[t + 512]; }  // 8 KB
  ld_B(0);
  ld_p1(0);
  __syncthreads();                  // edt_lds visible
  p1_compute(0);
  ld_p1(1);
  __syncthreads();                  // pew[0] visible

  // ---- main loop: NOT unrolled (keeps single-buffer regs single) ----
  #pragma unroll 1
  for (int c = 0; c < 8; ++c) {
    p2_step(c);                       // consumes B(c) + pew[c&1]
    if (c + 1 < 8) {
      ld_B(c + 1);                    // refill B; ~1 chunk in flight before use
      p1_compute(c + 1);              // consumes rmw(c+1), writes pew[(c+1)&1]
      if (c + 2 < 8) ld_p1(c + 2);    // refill rmw
      __syncthreads();
    }
  }

  // ---- denominators: reduce over the 32-lane half sharing il ----
  #pragma unroll
  for (int h = 0; h < 4; ++h) {
    float v = dpart[h];
    v += __shfl_xor(v, 1, 64);  v += __shfl_xor(v, 2, 64);
    v += __shfl_xor(v, 4, 64);  v += __shfl_xor(v, 8, 64);
    v += __shfl_xor(v, 16, 64);
    if (jq == 0) dvl[il * NH + h] = v;
  }
  __syncthreads();
  if (t < 64) { const float dd = dvl[t]; dvl[t] = dd > 0.f ? 1.0f / dd : 0.f; }
  __syncthreads();
  // ---- out = acc_sum * inv (fp32, proven) ----
  #pragma unroll
  for (int reg = 0; reg < 4; ++reg) {
    const int row = kq * 4 + reg;              // D: col=lane&15, row=quad*4+reg
    const float inv = dvl[row * NH + hh];
    out[((size_t)b * N + i0 + row) * FO + hh * 32 + nt2 * 16 + m]
        = (acc0[reg] + acc1[reg]) * inv;
  }
  // ---- fused avg tail (fp32 formula; edt from LDS, mew L1-hot) ----
  float inv4[4];
  #pragma unroll
  for (int h = 0; h < 4; ++h) inv4[h] = dvl[il * NH + h];
  #pragma unroll 1
  for (int c = 0; c < 8; ++c) {
    const int jb = c * 128 + jq * 4;
    union { uint2 v; unsigned short u[4]; } mw;
    mw.v = *(const uint2*)(mew + (size_t)gi * N + jb);
    float4 ed4[4];
    #pragma unroll
    for (int h = 0; h < 4; ++h)
      ed4[h] = *(const float4*)(&edt_lds[h * N + jb]);   // LDS broadcast
    float4 r;
    float* rp = &r.x;
    #pragma unroll
    for (int u = 0; u < 4; ++u) {
      const float mfa = h2f((unsigned short)(mw.u[u] & 0x7fff));
      float sv = 0.f;
      #pragma unroll
      for (int h = 0; h < 4; ++h) {
        float e = esv[h] + (&ed4[h].x)[u];
        e = fmaxf(e, 0.2f * e);
        sv += __builtin_amdgcn_exp2f(e) * inv4[h];
      }
      rp[u] = 0.25f * mfa * sv;            // masked: mfa=0 -> 0
    }
    *(float4*)(avg + ((size_t)b * N + gi) * N + jb) = r;
  }
}

// ---------------------------------------------------------------------------
extern "C" void kernel_launch(void* const* d_in, const int* in_sizes, int n_in,
                              void* d_out, int out_size, void* d_ws, size_t ws_size,
                              hipStream_t stream) {
  const float* x   = (const float*)d_in[0];
  const int*   adj = (const int*)d_in[1];
  const float* ewt = (const float*)d_in[2];
  const float* W   = (const float*)d_in[3];
  const float* a   = (const float*)d_in[4];

  float* out = (float*)d_out;                  // [B,N,128]
  float* avg = out + (size_t)B * N * FO;       // [B,N,N]

  unsigned short* h16 = (unsigned short*)d_ws;        // h fp16 frag, 2 MB
  unsigned short* mew = h16 + (size_t)B * FO * N;     // [N,N] fp16 masked, 2 MB
  float* es   = (float*)(mew + (size_t)N * N);        // [B*N, 4]
  float* edt  = es + (size_t)B * N * NH;              // [B, 4, N]

  gat_prep<<<1024, 256, 0, stream>>>(x, W, a, adj, ewt, h16, es, edt, mew);
  gat_attn<<<B * (N / 16), 512, 0, stream>>>(h16, es, edt, mew, out, avg);
}